// Round 7
// baseline (2181.791 us; speedup 1.0000x reference)
//
#include <hip/hip_runtime.h>
#include <stdint.h>

// LSTM_Trend: B=256, T=512, F=64, H=512, P=24.
// Persistent kernel: 256 WGs x 256 threads (1/CU) = 16 batch-groups x 16
// hidden-groups. Weights register-resident as MFMA B-fragments (144 VGPRs).
//
// R7 = R6 + sched_barrier(0) fences (guide rule #18). R6's register-direct
// structure (LDS A-tile deleted; h A-frags ld128'd straight from the packed
// h layout in the XCD L2; 1 barrier/step; per-wave flags) failed correctness
// because hipcc hoists REGISTER-ONLY consumers (MFMA, VALU compares) past an
// inline-asm s_waitcnt vmcnt(0) -- the "memory" clobber doesn't order
// non-memory instructions. Fix: __builtin_amdgcn_sched_barrier(0)
// immediately after each inline-asm waitcnt whose consumers are
// register-only (poll flag compares, h-MFMA block, FC-head MFMAs).
// Everything else is byte-identical to R6:
//  - transport: XCD-local sc0 stores (rendezvous-verified, R4: WRITE_SIZE
//    137->2 MB), sc0sc1 loads hit dirty local-L2 lines; fallback sc0sc1.
//  - packed h dword layout row*256 + p*16 + kq*4 IS the MFMA A-fragment
//    layout -> lane (nl,kq) ld128s fragments directly, no LDS staging.
//  - flag semantics: value v = h for MFMA-step v ready in parity v&1;
//    act(t) stores h(t) to parity (t+1)&1, drains (wave vmcnt(0)),
//    publishes t+2. Overwrite-safe: act(t) clobbers h(t-2); any WG's flag
//    >= t+1 implies it passed its step t-1 barrier, hence finished its
//    step t-1 loads of h(t-2); producer observed ALL flags >= t+1 at its
//    step-t poll before act(t).
//  - ONE __syncthreads/step (Gls write -> act read; Gls double-buffered).

namespace {
constexpr int T_STEPS = 512;
constexpr int FEA  = 64;
constexpr int HID  = 512;
constexpr int NKI  = 18;          // 16 h k-iters + 2 x k-iters
constexpr int GSTR = 132;         // gates LDS row stride (floats)
constexpr int RPG  = 16;          // batch rows per group
constexpr size_t HBUF_DW = 256ull * 256;      // packed h dwords per parity
constexpr size_t FLAG_OFF = 2 * HBUF_DW;      // 16 groups x 64 wave-flags
constexpr size_t GRZ_OFF  = FLAG_OFF + 16 * 64;  // gmask[16], gcnt[16]

typedef __bf16   bf16x8 __attribute__((ext_vector_type(8)));
typedef uint16_t u16x8  __attribute__((ext_vector_type(8)));
typedef float    f32x4  __attribute__((ext_vector_type(4)));
typedef uint32_t u32x4  __attribute__((ext_vector_type(4)));

union V8 { u16x8 u; bf16x8 b; u32x4 q; };

__device__ __forceinline__ float bf2f(uint16_t u) {
  union { uint32_t i; float f; } v; v.i = (uint32_t)u << 16; return v.f;
}
__device__ __forceinline__ uint16_t f2bf(float f) {
  union { float f; uint32_t i; } v; v.f = f;
  uint32_t x = v.i;
  return (uint16_t)((x + 0x7FFFu + ((x >> 16) & 1u)) >> 16);  // RNE
}
__device__ __forceinline__ float sigmoid_f(float x) {
  return 1.0f / (1.0f + __expf(-x));
}
__device__ __forceinline__ float tanh_f(float x) {
  float e = __expf(-2.0f * fabsf(x));
  float t = (1.0f - e) / (1.0f + e);
  return copysignf(t, x);
}
__device__ __forceinline__ bf16x8 load8(const void* base, size_t elem_off,
                                        bool fp32m) {
  V8 r;
  if (fp32m) {
    const float* p = (const float*)base + elem_off;
#pragma unroll
    for (int i = 0; i < 8; ++i) r.u[i] = f2bf(p[i]);
  } else {
    r.q = *(const u32x4*)((const uint16_t*)base + elem_off);
  }
  return r.b;
}
__device__ __forceinline__ float loadf(const void* base, int idx, bool fp32m) {
  return fp32m ? ((const float*)base)[idx] : bf2f(((const uint16_t*)base)[idx]);
}

// ---- exchange memory ops --------------------------------------------------
__device__ __forceinline__ uint32_t ld32_sc01(const uint32_t* p) {
  uint32_t v;
  asm volatile("global_load_dword %0, %1, off sc0 sc1"
               : "=v"(v) : "v"(p) : "memory");
  return v;
}
__device__ __forceinline__ u32x4 ld128_sc01(const uint32_t* p) {
  u32x4 v;
  asm volatile("global_load_dwordx4 %0, %1, off sc0 sc1"
               : "=v"(v) : "v"(p) : "memory");
  return v;
}
__device__ __forceinline__ void st32_x(uint32_t* p, uint32_t v, bool xl) {
  if (xl) asm volatile("global_store_dword %0, %1, off sc0"
                       :: "v"(p), "v"(v) : "memory");
  else    asm volatile("global_store_dword %0, %1, off sc0 sc1"
                       :: "v"(p), "v"(v) : "memory");
}
// waitcnt + hard scheduling fence: rule #18 -- hipcc hoists register-only
// consumers (MFMA/VALU) past inline-asm s_waitcnt; sched_barrier(0) pins.
__device__ __forceinline__ void waitcnt_vm0_fence() {
  asm volatile("s_waitcnt vmcnt(0)" ::: "memory");
  __builtin_amdgcn_sched_barrier(0);
}
__device__ __forceinline__ void waitcnt_vm0() {
  asm volatile("s_waitcnt vmcnt(0)" ::: "memory");
}
} // namespace

__global__ __launch_bounds__(256, 1) void lstm_persistent(
    const void* __restrict__ x,      // [256][512][64]
    const void* __restrict__ W_ih,   // [2048][64]
    const void* __restrict__ W_hh,   // [2048][512]
    const void* __restrict__ b_ih,   // [2048]
    const void* __restrict__ b_hh,   // [2048]
    const void* __restrict__ W_fc,   // [1536][512]
    const void* __restrict__ b_fc,   // [1536]
    void* __restrict__ out,          // [256][1536]
    uint32_t* __restrict__ dbuf)     // ws: [2][256][256] h + flags + rdzv
{
  __shared__ float Gls[2][RPG * GSTR];   // gate pre-activations, 2 buffers
  __shared__ int   sflag, sok;

  const int tid = threadIdx.x;
  const int wv  = tid >> 6;              // wave 0..3
  const int ln  = tid & 63;
  const int nl  = ln & 15;               // MFMA m/n lane index (row)
  const int kq  = ln >> 4;               // MFMA k-quad
  const int bg  = blockIdx.x & 15;       // batch group
  const int wgi = blockIdx.x >> 4;       // hidden group 0..15
  const int r0  = bg * RPG;              // first batch row of this group

  // ---- per-group XCD-identity rendezvous (one-time, R4-proven) ------------
  if (tid == 0) {
    uint32_t xcc;
    asm volatile("s_getreg_b32 %0, hwreg(HW_REG_XCC_ID)" : "=s"(xcc));
    unsigned* gmask = (unsigned*)(dbuf + GRZ_OFF) + bg;
    unsigned* gcnt  = (unsigned*)(dbuf + GRZ_OFF) + 16 + bg;
    atomicOr(gmask, 1u << (xcc & 31));
    __threadfence();
    atomicAdd(gcnt, 1u);
    while (atomicAdd(gcnt, 0u) < 16u) __builtin_amdgcn_s_sleep(1);
    __threadfence();
    unsigned m = atomicOr(gmask, 0u);
    sok = (__popc(m) == 1) ? 1 : 0;
  }

  // ---- dtype sniff (block-uniform): fp32 read as bf16 -> huge exponents
  if (tid == 1) sflag = 0;
  __syncthreads();
  {
    float a = fabsf(bf2f(((const uint16_t*)b_ih)[tid]));
    if (a > 1.0f) atomicOr(&sflag, 1);
  }
  __syncthreads();
  const bool fp32m = (sflag != 0);
  const bool xloc  = (sok != 0);

  // wave owns cols [wv*32, wv*32+32) as two 16-col subtiles sharing one A-frag
  bf16x8 breg[2][NKI];
  float  bias[2];
#pragma unroll
  for (int s = 0; s < 2; ++s) {
    int col  = wv * 32 + s * 16 + nl;    // 0..127
    int gate = col & 3;
    int unit = col >> 2;                 // 0..31
    int gcol = gate * HID + wgi * 32 + unit;
#pragma unroll
    for (int kk = 0; kk < NKI; ++kk) {
      int k0 = kk * 32 + kq * 8;
      if (k0 < HID)
        breg[s][kk] = load8(W_hh, (size_t)gcol * HID + k0, fp32m);
      else
        breg[s][kk] = load8(W_ih, (size_t)gcol * FEA + (k0 - HID), fp32m);
    }
    bias[s] = loadf(b_ih, gcol, fp32m) + loadf(b_hh, gcol, fp32m);
  }

  // act roles: row ar (0..15), own units au, au+1; wave wv covers ar 4wv..+4
  const int ar  = tid >> 4;
  const int au  = (tid & 15) * 2;
  const int hdw = (r0 + ar) * 256 + wgi * 16 + (tid & 15);  // packed h dword
  float c0 = 0.0f, c1 = 0.0f;

  uint32_t* flagw = dbuf + FLAG_OFF + bg * 64 + wgi * 4 + wv;   // producer
  const uint32_t* fb = dbuf + FLAG_OFF + bg * 64 + (nl >> 2);   // consumer

  // ---- prologue: h(-1) = 0 -> parity 0; publish per-wave flag = 1 ----
  st32_x(dbuf + hdw, 0u, xloc);
  waitcnt_vm0();
  if (ln == 0) st32_x(flagw, 1u, xloc);

  for (int t = 0; t < T_STEPS; ++t) {
    // ---- x A-frags for k=16,17 (plain cached loads; read-only data) ----
    bf16x8 ax0, ax1;
    {
      size_t off = (size_t)(r0 + nl) * (T_STEPS * FEA) + (size_t)t * FEA
                 + kq * 8;
      if (fp32m) {
        const float* xp = (const float*)x + off;
        V8 a0v, a1v;
#pragma unroll
        for (int i = 0; i < 8; ++i) {
          a0v.u[i] = f2bf(xp[i]); a1v.u[i] = f2bf(xp[32 + i]);
        }
        ax0 = a0v.b; ax1 = a1v.b;
      } else {
        const uint16_t* xp = (const uint16_t*)x + off;
        ax0 = *(const bf16x8*)xp;
        ax1 = *(const bf16x8*)(xp + 32);
      }
    }

    // ---- poll per-wave flags: chunk p ready iff flag[p][nl>>2] >= t+1 ----
    {
      const uint32_t tgt = (uint32_t)(t + 1);
      uint32_t need = 0xFFFFu;
      uint32_t fv[16];
      for (;;) {
#pragma unroll
        for (int p = 0; p < 16; ++p)
          if (need & (1u << p)) fv[p] = ld32_sc01(fb + p * 4);
        waitcnt_vm0_fence();             // fence: compares are register-only
#pragma unroll
        for (int p = 0; p < 16; ++p)
          if ((need & (1u << p)) && fv[p] >= tgt) need &= ~(1u << p);
        if (!need) break;
      }
    }

    // ---- batch-issue 16 h A-frag loads (L2-dirty lines, one RTT) ----
    const uint32_t* hb = dbuf + (size_t)(t & 1) * HBUF_DW
                       + (size_t)(r0 + nl) * 256 + kq * 4;
    V8 av[16];
#pragma unroll
    for (int p = 0; p < 16; ++p) av[p].q = ld128_sc01(hb + p * 16);

    // ---- x MFMAs while h loads are in flight ----
    f32x4 c0a, c0b, c1a, c1b;
#pragma unroll
    for (int i = 0; i < 4; ++i) {
      c0a[i] = bias[0]; c1a[i] = bias[1]; c0b[i] = 0.0f; c1b[i] = 0.0f;
    }
    c0a = __builtin_amdgcn_mfma_f32_16x16x32_bf16(ax0, breg[0][16], c0a, 0, 0, 0);
    c1a = __builtin_amdgcn_mfma_f32_16x16x32_bf16(ax0, breg[1][16], c1a, 0, 0, 0);
    c0b = __builtin_amdgcn_mfma_f32_16x16x32_bf16(ax1, breg[0][17], c0b, 0, 0, 0);
    c1b = __builtin_amdgcn_mfma_f32_16x16x32_bf16(ax1, breg[1][17], c1b, 0, 0, 0);
    waitcnt_vm0_fence();                 // fence: h-MFMAs are register-only

    // ---- 32 h MFMAs, 4 accumulator chains (halved dep depth) ----
#pragma unroll
    for (int kk = 0; kk < 16; ++kk) {
      if (kk & 1) {
        c0b = __builtin_amdgcn_mfma_f32_16x16x32_bf16(av[kk].b, breg[0][kk], c0b, 0, 0, 0);
        c1b = __builtin_amdgcn_mfma_f32_16x16x32_bf16(av[kk].b, breg[1][kk], c1b, 0, 0, 0);
      } else {
        c0a = __builtin_amdgcn_mfma_f32_16x16x32_bf16(av[kk].b, breg[0][kk], c0a, 0, 0, 0);
        c1a = __builtin_amdgcn_mfma_f32_16x16x32_bf16(av[kk].b, breg[1][kk], c1a, 0, 0, 0);
      }
    }
    f32x4 A0 = c0a + c0b, A1 = c1a + c1b;

    // ---- gate pre-activations -> Gls[t&1] ----
    float* G = Gls[t & 1];
#pragma unroll
    for (int r = 0; r < 4; ++r) {
      G[(kq * 4 + r) * GSTR + wv * 32 + nl]      = A0[r];
      G[(kq * 4 + r) * GSTR + wv * 32 + 16 + nl] = A1[r];
    }
    __syncthreads();                     // the ONE barrier per step

    // ---- activations, cell update; h store; wave-drain; wave flag ----
    {
      const f32x4* gp = (const f32x4*)&Gls[t & 1][ar * GSTR + au * 4];
      f32x4 ga = gp[0], gb = gp[1];
      c0 = sigmoid_f(ga[1]) * c0 + sigmoid_f(ga[0]) * tanh_f(ga[2]);
      float h0 = sigmoid_f(ga[3]) * tanh_f(c0);
      c1 = sigmoid_f(gb[1]) * c1 + sigmoid_f(gb[0]) * tanh_f(gb[2]);
      float h1 = sigmoid_f(gb[3]) * tanh_f(c1);
      uint32_t hp = (uint32_t)f2bf(h0) | ((uint32_t)f2bf(h1) << 16);
      st32_x(dbuf + (size_t)((t + 1) & 1) * HBUF_DW + hdw, hp, xloc);
      waitcnt_vm0();                     // wave's stores drained to L2
      if (ln == 0) st32_x(flagw, (uint32_t)(t + 2), xloc);
    }
  }

  // ---- FC head: out = h_T @ W_fc^T + b_fc  (h_T in parity 0, flag 513) ----
  {
    const uint32_t tgt = (uint32_t)(T_STEPS + 1);
    uint32_t need = 0xFFFFu;
    uint32_t fv[16];
    for (;;) {
#pragma unroll
      for (int p = 0; p < 16; ++p)
        if (need & (1u << p)) fv[p] = ld32_sc01(fb + p * 4);
      waitcnt_vm0_fence();               // fence: compares are register-only
#pragma unroll
      for (int p = 0; p < 16; ++p)
        if ((need & (1u << p)) && fv[p] >= tgt) need &= ~(1u << p);
      if (!need) break;
    }
  }
  int gwave = wgi * 4 + wv;              // 0..63 within the batch group
  for (int tile = gwave; tile < 96; tile += 64) {
    int n = tile * 16 + nl;              // out column
    float bs = loadf(b_fc, n, fp32m);
    f32x4 acc; acc[0] = bs; acc[1] = bs; acc[2] = bs; acc[3] = bs;
    const uint32_t* hb = dbuf + (size_t)(r0 + nl) * 256 + kq * 4;
    V8 av[16];
#pragma unroll
    for (int p = 0; p < 16; ++p) av[p].q = ld128_sc01(hb + p * 16);
    waitcnt_vm0_fence();                 // fence: MFMAs are register-only
#pragma unroll
    for (int kk = 0; kk < 16; ++kk) {
      bf16x8 b = load8(W_fc, (size_t)n * HID + kk * 32 + kq * 8, fp32m);
      acc = __builtin_amdgcn_mfma_f32_16x16x32_bf16(av[kk].b, b, acc, 0, 0, 0);
    }
#pragma unroll
    for (int r = 0; r < 4; ++r) {
      int row = r0 + kq * 4 + r;
      if (fp32m) ((float*)out)[(size_t)row * 1536 + n] = acc[r];
      else       ((uint16_t*)out)[(size_t)row * 1536 + n] = f2bf(acc[r]);
    }
  }
}

extern "C" void kernel_launch(void* const* d_in, const int* in_sizes, int n_in,
                              void* d_out, int out_size, void* d_ws, size_t ws_size,
                              hipStream_t stream) {
  const void* x    = d_in[0];
  const void* W_ih = d_in[1];
  const void* W_hh = d_in[2];
  const void* b_ih = d_in[3];
  const void* b_hh = d_in[4];
  const void* W_fc = d_in[5];
  const void* b_fc = d_in[6];
  uint32_t* dbuf = (uint32_t*)d_ws;

  // flags (16x64 dwords) + rendezvous (gmask[16], gcnt[16]) start at 0 each
  // call; h parity buffers are zeroed by the kernel prologue (flag-gated).
  hipMemsetAsync((void*)(dbuf + FLAG_OFF), 0,
                 (16 * 64 + 32) * sizeof(uint32_t), stream);

  lstm_persistent<<<dim3(256), dim3(256), 0, stream>>>(
      x, W_ih, W_hh, b_ih, b_hh, W_fc, b_fc, d_out, dbuf);
}

// Round 8
// 1033.440 us; speedup vs baseline: 2.1112x; 2.1112x over previous
//
#include <hip/hip_runtime.h>
#include <stdint.h>

// LSTM_Trend: B=256, T=512, F=64, H=512, P=24.
// Persistent kernel: 256 WGs x 256 threads (1/CU) = 16 batch-groups x 16
// hidden-groups. Weights register-resident as MFMA B-fragments (144 VGPRs).
//
// R8 = R4 (1042us, proven) + two targeted fixes; transport untouched
// (XCD-local sc0 stores verified by rendezvous, WRITE_SIZE 137->2MB;
// sc0sc1 loads hit dirty local-L2 lines; R7 showed register-direct loses).
//  1. FRAG-MAJOR A-TILE, 272B granule pitch: A-fragment (granule g=4*kk+kq,
//     row r) lives at byte g*272 + r*16. MFMA ds_read_b128: lanes (nl,kq)
//     hit bank-sets (g+nl)&7 -> uniform 8 lanes/set = conflict-free (R4's
//     row-major stride 1168B was an 8-way conflict, 3.8e7 conflict-cycles).
//     Bulk-load ds_writes (row=tid>>4, c=tid&15): sets (c+row)&7 -> uniform,
//     also conflict-free; global reads stay 256B-coalesced. The 272B pitch
//     (17 x 16B) breaks mod-32-dword alignment; no swizzle arithmetic.
//  2. PER-WAVE FLAGS (R6's producer protocol -- the side that was always
//     correct): act wave stores h, drains ITS OWN stores (vmcnt(0)), lane 0
//     publishes flag t+1. Drops R4's S3 barrier + WG-wide drain -> 3
//     barriers/step. Poll: 16 lanes x ld128 over the 64-flag line, with
//     sched_barrier(0) after the inline-asm waitcnt (rule #18: compares are
//     register-only and get hoisted otherwise; R6's failure, R7's fix).
// Overwrite safety (parity reuse after 2 steps) unchanged: flag t+2 from a
// WG implies it passed S1(t+1), hence its bulk(t) loads completed; producer
// observes all flags >= t+2 at poll(t+1) before act(t+2) overwrites.

namespace {
constexpr int T_STEPS = 512;
constexpr int FEA  = 64;
constexpr int HID  = 512;
constexpr int NKI  = 18;          // 16 h k-iters + 2 x k-iters
constexpr int GSTR = 132;         // gates LDS row stride (floats)
constexpr int RPG  = 16;          // batch rows per group
constexpr int GPITCH = 136;       // uint16 elems per granule group (272 B)
constexpr size_t HBUF_DW  = 256ull * 256;       // packed h dwords per parity
constexpr size_t FLAG_OFF = 2 * HBUF_DW;        // 16 groups x 64 wave-flags
constexpr size_t GRZ_OFF  = FLAG_OFF + 16 * 64; // gmask[16], gcnt[16]

typedef __bf16   bf16x8 __attribute__((ext_vector_type(8)));
typedef uint16_t u16x8  __attribute__((ext_vector_type(8)));
typedef float    f32x4  __attribute__((ext_vector_type(4)));
typedef uint32_t u32x4  __attribute__((ext_vector_type(4)));

union V8 { u16x8 u; bf16x8 b; u32x4 q; };

__device__ __forceinline__ float bf2f(uint16_t u) {
  union { uint32_t i; float f; } v; v.i = (uint32_t)u << 16; return v.f;
}
__device__ __forceinline__ uint16_t f2bf(float f) {
  union { float f; uint32_t i; } v; v.f = f;
  uint32_t x = v.i;
  return (uint16_t)((x + 0x7FFFu + ((x >> 16) & 1u)) >> 16);  // RNE
}
__device__ __forceinline__ float sigmoid_f(float x) {
  return 1.0f / (1.0f + __expf(-x));
}
__device__ __forceinline__ float tanh_f(float x) {
  float e = __expf(-2.0f * fabsf(x));
  float t = (1.0f - e) / (1.0f + e);
  return copysignf(t, x);
}
__device__ __forceinline__ bf16x8 load8(const void* base, size_t elem_off,
                                        bool fp32m) {
  V8 r;
  if (fp32m) {
    const float* p = (const float*)base + elem_off;
#pragma unroll
    for (int i = 0; i < 8; ++i) r.u[i] = f2bf(p[i]);
  } else {
    r.q = *(const u32x4*)((const uint16_t*)base + elem_off);
  }
  return r.b;
}
__device__ __forceinline__ float loadf(const void* base, int idx, bool fp32m) {
  return fp32m ? ((const float*)base)[idx] : bf2f(((const uint16_t*)base)[idx]);
}
__device__ __forceinline__ uint2 ldx4(const void* x, size_t elem_off,
                                      bool fp32m) {  // 4 x-vals -> 4 bf16
  if (fp32m) {
    float4 v = *(const float4*)((const float*)x + elem_off);
    uint2 w;
    w.x = (uint32_t)f2bf(v.x) | ((uint32_t)f2bf(v.y) << 16);
    w.y = (uint32_t)f2bf(v.z) | ((uint32_t)f2bf(v.w) << 16);
    return w;
  }
  return *(const uint2*)((const uint16_t*)x + elem_off);
}

// ---- exchange memory ops --------------------------------------------------
__device__ __forceinline__ u32x4 ld128_sc01(const uint32_t* p) {
  u32x4 v;
  asm volatile("global_load_dwordx4 %0, %1, off sc0 sc1"
               : "=v"(v) : "v"(p) : "memory");
  return v;
}
__device__ __forceinline__ void st32_x(uint32_t* p, uint32_t v, bool xl) {
  if (xl) asm volatile("global_store_dword %0, %1, off sc0"
                       :: "v"(p), "v"(v) : "memory");
  else    asm volatile("global_store_dword %0, %1, off sc0 sc1"
                       :: "v"(p), "v"(v) : "memory");
}
__device__ __forceinline__ void waitcnt_vm0() {
  asm volatile("s_waitcnt vmcnt(0)" ::: "memory");
}
// rule #18: register-only consumers (compares/MFMA) get hoisted past an
// inline-asm waitcnt; sched_barrier(0) pins them.
__device__ __forceinline__ void waitcnt_vm0_fence() {
  asm volatile("s_waitcnt vmcnt(0)" ::: "memory");
  __builtin_amdgcn_sched_barrier(0);
}
} // namespace

__global__ __launch_bounds__(256, 1) void lstm_persistent(
    const void* __restrict__ x,      // [256][512][64]
    const void* __restrict__ W_ih,   // [2048][64]
    const void* __restrict__ W_hh,   // [2048][512]
    const void* __restrict__ b_ih,   // [2048]
    const void* __restrict__ b_hh,   // [2048]
    const void* __restrict__ W_fc,   // [1536][512]
    const void* __restrict__ b_fc,   // [1536]
    void* __restrict__ out,          // [256][1536]
    uint32_t* __restrict__ dbuf)     // ws: [2][256][256] h + flags + rdzv
{
  __shared__ __align__(16) uint16_t Als[72 * GPITCH];  // frag-major A tile
  __shared__ float Gls[RPG * GSTR];     // gate pre-activations
  __shared__ int   sflag, sok;

  const int tid = threadIdx.x;
  const int wv  = tid >> 6;              // wave 0..3
  const int ln  = tid & 63;
  const int nl  = ln & 15;               // MFMA m/n lane index (row)
  const int kq  = ln >> 4;               // MFMA k-quad
  const int bg  = blockIdx.x & 15;       // batch group
  const int wgi = blockIdx.x >> 4;       // hidden group 0..15
  const int r0  = bg * RPG;              // first batch row of this group

  // ---- per-group XCD-identity rendezvous (one-time, R4-proven) ------------
  if (tid == 0) {
    uint32_t xcc;
    asm volatile("s_getreg_b32 %0, hwreg(HW_REG_XCC_ID)" : "=s"(xcc));
    unsigned* gmask = (unsigned*)(dbuf + GRZ_OFF) + bg;
    unsigned* gcnt  = (unsigned*)(dbuf + GRZ_OFF) + 16 + bg;
    atomicOr(gmask, 1u << (xcc & 31));
    __threadfence();
    atomicAdd(gcnt, 1u);
    while (atomicAdd(gcnt, 0u) < 16u) __builtin_amdgcn_s_sleep(1);
    __threadfence();
    unsigned m = atomicOr(gmask, 0u);
    sok = (__popc(m) == 1) ? 1 : 0;
  }

  // ---- dtype sniff (block-uniform): fp32 read as bf16 -> huge exponents
  if (tid == 1) sflag = 0;
  __syncthreads();
  {
    float a = fabsf(bf2f(((const uint16_t*)b_ih)[tid]));
    if (a > 1.0f) atomicOr(&sflag, 1);
  }
  __syncthreads();
  const bool fp32m = (sflag != 0);
  const bool xloc  = (sok != 0);

  // wave owns cols [wv*32, wv*32+32) as two 16-col subtiles sharing one A-frag
  bf16x8 breg[2][NKI];
  float  bias[2];
#pragma unroll
  for (int s = 0; s < 2; ++s) {
    int col  = wv * 32 + s * 16 + nl;    // 0..127
    int gate = col & 3;
    int unit = col >> 2;                 // 0..31
    int gcol = gate * HID + wgi * 32 + unit;
#pragma unroll
    for (int kk = 0; kk < NKI; ++kk) {
      int k0 = kk * 32 + kq * 8;
      if (k0 < HID)
        breg[s][kk] = load8(W_hh, (size_t)gcol * HID + k0, fp32m);
      else
        breg[s][kk] = load8(W_ih, (size_t)gcol * FEA + (k0 - HID), fp32m);
    }
    bias[s] = loadf(b_ih, gcol, fp32m) + loadf(b_hh, gcol, fp32m);
  }

  // act roles: row ar (0..15), units au, au+1; wave wv covers ar = 4wv..4wv+3
  const int ar  = tid >> 4;
  const int au  = (tid & 15) * 2;
  const int hdw = (r0 + ar) * 256 + wgi * 16 + (tid & 15);  // packed h dword
  float c0 = 0.0f, c1 = 0.0f;

  // staging roles: row = tid>>4, c = tid&15 (granule class)
  const int srow = tid >> 4;
  const int sc   = tid & 15;

  uint32_t* flagw = dbuf + FLAG_OFF + bg * 64 + wgi * 4 + wv;   // producer
  // consumer: lane i (i<16) checks producer i's 4 wave-flags via one ld128
  const uint32_t* fb0 = dbuf + FLAG_OFF + bg * 64;

  // ---- prologue: h(0)=0 in LDS (frag-major h region), stage x(0) ----
  {
    u32x4 z = {0, 0, 0, 0};
    for (int i = tid; i < 64 * GPITCH / 8; i += 256)
      *(u32x4*)&Als[i * 8] = z;
  }
  {
    int gx = sc & 7, hf = sc >> 3;
    size_t off = (size_t)(r0 + srow) * (T_STEPS * FEA) + gx * 8 + hf * 4;
    uint2 w = ldx4(x, off, fp32m);
    *(uint2*)&Als[(64 + gx) * GPITCH + srow * 8 + hf * 4] = w;
  }

  for (int t = 0; t < T_STEPS; ++t) {
    __syncthreads();                     // S1: A tile staged

    // ---- gates = A @ W^T + bias: 18 ds_read_b128 (conflict-free) ----
    f32x4 acc0, acc1;
    acc0[0] = bias[0]; acc0[1] = bias[0]; acc0[2] = bias[0]; acc0[3] = bias[0];
    acc1[0] = bias[1]; acc1[1] = bias[1]; acc1[2] = bias[1]; acc1[3] = bias[1];
#pragma unroll
    for (int kk = 0; kk < NKI; ++kk) {
      bf16x8 a = *(const bf16x8*)&Als[(4 * kk + kq) * GPITCH + nl * 8];
      acc0 = __builtin_amdgcn_mfma_f32_16x16x32_bf16(a, breg[0][kk], acc0, 0, 0, 0);
      acc1 = __builtin_amdgcn_mfma_f32_16x16x32_bf16(a, breg[1][kk], acc1, 0, 0, 0);
    }
#pragma unroll
    for (int r = 0; r < 4; ++r) {
      Gls[(kq * 4 + r) * GSTR + wv * 32 + nl]      = acc0[r];
      Gls[(kq * 4 + r) * GSTR + wv * 32 + 16 + nl] = acc1[r];
    }
    __syncthreads();                     // S2: gates ready, A tile free

    const uint32_t tg = (uint32_t)(t + 1);
    const bool havex = (t + 1 < T_STEPS);

    // ---- act: cell update; h store; WAVE drain; per-wave flag ----
    {
      const f32x4* gp = (const f32x4*)&Gls[ar * GSTR + au * 4];
      f32x4 ga = gp[0], gb = gp[1];
      c0 = sigmoid_f(ga[1]) * c0 + sigmoid_f(ga[0]) * tanh_f(ga[2]);
      float h0 = sigmoid_f(ga[3]) * tanh_f(c0);
      c1 = sigmoid_f(gb[1]) * c1 + sigmoid_f(gb[0]) * tanh_f(gb[2]);
      float h1 = sigmoid_f(gb[3]) * tanh_f(c1);
      uint32_t hp = (uint32_t)f2bf(h0) | ((uint32_t)f2bf(h1) << 16);
      st32_x(dbuf + (size_t)(tg & 1) * HBUF_DW + hdw, hp, xloc);
      waitcnt_vm0();                     // this wave's h stores at L2
      if (ln == 0) st32_x(flagw, tg, xloc);
    }

    // ---- stage x(t+1) (x region free after S2; overlaps flag latency) ----
    if (havex) {
      int gx = sc & 7, hf = sc >> 3;
      size_t off = (size_t)(r0 + srow) * (T_STEPS * FEA)
                 + (size_t)(t + 1) * FEA + gx * 8 + hf * 4;
      uint2 w = ldx4(x, off, fp32m);
      *(uint2*)&Als[(64 + gx) * GPITCH + srow * 8 + hf * 4] = w;
    }

    // ---- poll: 16 lanes, one ld128 of 4 wave-flags each ----
    if (tid < 16) {
      const uint32_t* fp = fb0 + tid * 4;
      for (;;) {
        u32x4 f = ld128_sc01(fp);
        waitcnt_vm0_fence();             // fence: compares are register-only
        uint32_t mn = f[0];
        mn = f[1] < mn ? f[1] : mn;
        mn = f[2] < mn ? f[2] : mn;
        mn = f[3] < mn ? f[3] : mn;
        if (mn >= tg) break;
      }
    }
    __syncthreads();                     // S3: all h(t+1) visible in L2

    // ---- bulk h(t+1) -> frag-major LDS (coalesced global, cf writes) ----
    if (havex) {
      const uint32_t* src = dbuf + (size_t)(tg & 1) * HBUF_DW
                          + (size_t)(r0 + srow) * 256;
      u32x4 v0 = ld128_sc01(src + (sc + 0)  * 4);
      u32x4 v1 = ld128_sc01(src + (sc + 16) * 4);
      u32x4 v2 = ld128_sc01(src + (sc + 32) * 4);
      u32x4 v3 = ld128_sc01(src + (sc + 48) * 4);
      waitcnt_vm0();                     // LDS writes below (memory-ordered)
      *(u32x4*)&Als[(sc + 0)  * GPITCH + srow * 8] = v0;
      *(u32x4*)&Als[(sc + 16) * GPITCH + srow * 8] = v1;
      *(u32x4*)&Als[(sc + 32) * GPITCH + srow * 8] = v2;
      *(u32x4*)&Als[(sc + 48) * GPITCH + srow * 8] = v3;
    }
  }

  // ---- FC head: out = h_T @ W_fc^T + b_fc  (h_T in parity 0, flags>=512) --
  int gwave = wgi * 4 + wv;              // 0..63 within the batch group
  for (int tile = gwave; tile < 96; tile += 64) {
    int n = tile * 16 + nl;              // out column
    float bs = loadf(b_fc, n, fp32m);
    f32x4 acc; acc[0] = bs; acc[1] = bs; acc[2] = bs; acc[3] = bs;
    const uint32_t* hb = dbuf + (size_t)(r0 + nl) * 256 + kq * 4;
    V8 av[16];
#pragma unroll
    for (int p = 0; p < 16; ++p) av[p].q = ld128_sc01(hb + p * 16);
    waitcnt_vm0_fence();                 // fence: MFMAs are register-only
#pragma unroll
    for (int kk = 0; kk < 16; ++kk) {
      bf16x8 b = load8(W_fc, (size_t)n * HID + kk * 32 + kq * 8, fp32m);
      acc = __builtin_amdgcn_mfma_f32_16x16x32_bf16(av[kk].b, b, acc, 0, 0, 0);
    }
#pragma unroll
    for (int r = 0; r < 4; ++r) {
      int row = r0 + kq * 4 + r;
      if (fp32m) ((float*)out)[(size_t)row * 1536 + n] = acc[r];
      else       ((uint16_t*)out)[(size_t)row * 1536 + n] = f2bf(acc[r]);
    }
  }
}

extern "C" void kernel_launch(void* const* d_in, const int* in_sizes, int n_in,
                              void* d_out, int out_size, void* d_ws, size_t ws_size,
                              hipStream_t stream) {
  const void* x    = d_in[0];
  const void* W_ih = d_in[1];
  const void* W_hh = d_in[2];
  const void* b_ih = d_in[3];
  const void* b_hh = d_in[4];
  const void* W_fc = d_in[5];
  const void* b_fc = d_in[6];
  uint32_t* dbuf = (uint32_t*)d_ws;

  // flags (16x64 dwords) + rendezvous (gmask[16], gcnt[16]) start at 0 each
  // call (ws is poisoned 0xAA; poisoned gmask -> safe sc0sc1 fallback).
  hipMemsetAsync((void*)(dbuf + FLAG_OFF), 0,
                 (16 * 64 + 32) * sizeof(uint32_t), stream);

  lstm_persistent<<<dim3(256), dim3(256), 0, stream>>>(
      x, W_ih, W_hh, b_ih, b_hh, W_fc, b_fc, d_out, dbuf);
}